// Round 9
// baseline (693.595 us; speedup 1.0000x reference)
//
#include <hip/hip_runtime.h>
#include <hip/hip_bf16.h>
#include <cstdint>
#include <cstddef>

// ---------------- types / helpers ----------------
typedef __bf16 bf16x8 __attribute__((ext_vector_type(8)));
typedef float f32x4 __attribute__((ext_vector_type(4)));

__device__ __forceinline__ unsigned short f2bf(float f) {
  unsigned u = __float_as_uint(f);
  u += 0x7fffu + ((u >> 16) & 1u);   // RNE
  return (unsigned short)(u >> 16);
}
__device__ __forceinline__ float bf2f(unsigned short s) {
  return __uint_as_float(((unsigned)s) << 16);
}

// async global->LDS, 16B per lane, linear dest (wave-uniform base + lane*16)
__device__ __forceinline__ void gld_lds16(const void* g, void* l) {
  __builtin_amdgcn_global_load_lds(
      (const __attribute__((address_space(1))) void*)g,
      (__attribute__((address_space(3))) void*)l, 16, 0, 0);
}

#define BARM() do { __builtin_amdgcn_s_barrier(); asm volatile("" ::: "memory"); } while (0)
#define VMCNT(n) asm volatile("s_waitcnt vmcnt(" #n ")" ::: "memory")
#define LGKM0()  do { asm volatile("s_waitcnt lgkmcnt(0)" ::: "memory"); \
                      __builtin_amdgcn_sched_barrier(0); } while (0)

// ---------------- transpose + convert W [K][N] f32 -> Wt [N][K] bf16 ----------------
__global__ void transpose_w(const float* __restrict__ w, unsigned short* __restrict__ wt,
                            int K, int N) {
  __shared__ float tile[32][33];
  int nt = N >> 5;
  int bx = blockIdx.x % nt;   // n tile
  int by = blockIdx.x / nt;   // k tile
  int tx = threadIdx.x & 31, ty = threadIdx.x >> 5;  // 32x8
#pragma unroll
  for (int r = 0; r < 32; r += 8)
    tile[ty + r][tx] = w[(size_t)(by * 32 + ty + r) * N + bx * 32 + tx];
  __syncthreads();
#pragma unroll
  for (int r = 0; r < 32; r += 8)
    wt[(size_t)(bx * 32 + ty + r) * K + by * 32 + tx] = f2bf(tile[tx][ty + r]);
}

// ---------------- 256x256 8-phase GEMM core (round-4 proven) ----------------
__device__ __forceinline__ bf16x8 read_frag(const unsigned short* region, int row, int kel) {
  int ke = kel ^ (((row >> 1) & 3) << 3);
  return *(const bf16x8*)(region + row * 32 + ke);
}

__device__ __forceinline__ void stage_half(const unsigned short* gpanel, int K, int kofs,
                                           unsigned short* region, int tid) {
#pragma unroll
  for (int r = 0; r < 2; ++r) {
    int row = r * 128 + (tid >> 2);
    int ke = ((tid & 3) * 8) ^ (((row >> 1) & 3) << 3);  // inverse-swizzled source
    gld_lds16(gpanel + (size_t)row * K + kofs + ke, region + r * 4096 + tid * 8);
  }
}

// f32-source A staging for the fused L0 (reg-stage: issue early, commit late)
__device__ __forceinline__ void issue_a(const float* xpanel, int K, int kofs, int tid,
                                        int lim, float4 (&rv)[4]) {
#pragma unroll
  for (int r = 0; r < 2; ++r) {
    int row = r * 128 + (tid >> 2);
    int rc = row < lim ? row : 0;      // clamp: never read past x's end
    int ke = ((tid & 3) * 8) ^ (((row >> 1) & 3) << 3);
    const float* g = xpanel + (size_t)rc * K + kofs + ke;
    rv[r * 2] = *(const float4*)g;
    rv[r * 2 + 1] = *(const float4*)(g + 4);
  }
}

__device__ __forceinline__ void commit_a(const float4 (&rv)[4], unsigned short* region,
                                         int tid, int lim) {
#pragma unroll
  for (int r = 0; r < 2; ++r) {
    int row = r * 128 + (tid >> 2);
    uint4 o;
    if (row < lim) {
      float4 v0 = rv[r * 2], v1 = rv[r * 2 + 1];
      __hip_bfloat162 p0 = __float22bfloat162_rn(float2{v0.x, v0.y});
      __hip_bfloat162 p1 = __float22bfloat162_rn(float2{v0.z, v0.w});
      __hip_bfloat162 p2 = __float22bfloat162_rn(float2{v1.x, v1.y});
      __hip_bfloat162 p3 = __float22bfloat162_rn(float2{v1.z, v1.w});
      o.x = *(unsigned*)&p0; o.y = *(unsigned*)&p1;
      o.z = *(unsigned*)&p2; o.w = *(unsigned*)&p3;
    } else {
      o.x = o.y = o.z = o.w = 0u;      // zero-pad rows >= Nn
    }
    *(uint4*)(region + r * 4096 + tid * 8) = o;   // linear dest, ds_write_b128
  }
}

#define MFMA16(MB, BV)                                                          \
  do {                                                                          \
    __builtin_amdgcn_s_setprio(1);                                              \
    _Pragma("unroll") for (int mm = 0; mm < 4; ++mm) {                          \
      _Pragma("unroll") for (int nn = 0; nn < 4; ++nn)                          \
        acc[(MB) + mm][nn] = __builtin_amdgcn_mfma_f32_16x16x32_bf16(           \
            av[mm], BV[nn], acc[(MB) + mm][nn], 0, 0, 0);                       \
    }                                                                           \
    __builtin_amdgcn_s_setprio(0);                                              \
  } while (0)

// Shared K-loop body (bf16 A via global_load_lds) — r4-proven.
#define GEMM_PREAMBLE_AND_KLOOP()                                               \
  const int tid = threadIdx.x;                                                  \
  const int w = tid >> 6, l = tid & 63;                                         \
  const int wm = w >> 2, wn = w & 3;                                            \
  const int lc = l & 15, lk8 = (l >> 4) * 8;                                    \
  const int nbn = N >> 8;                                                       \
  const int nwg = gridDim.x;                                                    \
  const int q = nwg >> 3, rr = nwg & 7;                                         \
  const int xcd = blockIdx.x & 7, ib = blockIdx.x >> 3;                         \
  const int bswz = (xcd < rr ? xcd * (q + 1) : rr * (q + 1) + (xcd - rr) * q) + ib; \
  const int bm = bswz / nbn, bn = bswz - bm * nbn;                              \
  const unsigned short* Ap = A + (size_t)bm * 256 * K;                          \
  const unsigned short* Bp = Bt + (size_t)bn * 256 * K;                         \
  const int T = K >> 6;                                                         \
  f32x4 acc[8][4] = {};                                                         \
  stage_half(Ap, K, 0, &lds[0][0][0][0][0], tid);                               \
  stage_half(Bp, K, 0, &lds[0][1][0][0][0], tid);                               \
  stage_half(Ap, K, 32, &lds[0][0][1][0][0], tid);                              \
  stage_half(Bp, K, 32, &lds[0][1][1][0][0], tid);                              \
  stage_half(Ap, K, 64, &lds[1][0][0][0][0], tid);                              \
  stage_half(Bp, K, 64, &lds[1][1][0][0][0], tid);                              \
  VMCNT(4);                                                                     \
  BARM();                                                                       \
  for (int t = 0; t < T; ++t) {                                                 \
    const int s = t & 1;                                                        \
    const unsigned short* Ak0 = &lds[s][0][0][0][0];                            \
    const unsigned short* Ak1 = &lds[s][0][1][0][0];                            \
    const unsigned short* Bk0 = &lds[s][1][0][0][0];                            \
    const unsigned short* Bk1 = &lds[s][1][1][0][0];                            \
    unsigned short* nAk1 = &lds[s ^ 1][0][1][0][0];                             \
    unsigned short* nBk1 = &lds[s ^ 1][1][1][0][0];                             \
    unsigned short* cAk0 = &lds[s][0][0][0][0];                                 \
    unsigned short* cBk0 = &lds[s][1][0][0][0];                                 \
    bf16x8 av[4], b0[4], b1[4];                                                 \
    _Pragma("unroll") for (int mm = 0; mm < 4; ++mm)                            \
        av[mm] = read_frag(Ak0, wm * 128 + mm * 16 + lc, lk8);                  \
    _Pragma("unroll") for (int nn = 0; nn < 4; ++nn)                            \
        b0[nn] = read_frag(Bk0, wn * 64 + nn * 16 + lc, lk8);                   \
    if (t + 1 < T) stage_half(Ap, K, (t + 1) * 64 + 32, nAk1, tid);             \
    BARM(); LGKM0(); MFMA16(0, b0); BARM();                                     \
    _Pragma("unroll") for (int mm = 0; mm < 4; ++mm)                            \
        av[mm] = read_frag(Ak0, wm * 128 + (4 + mm) * 16 + lc, lk8);            \
    if (t + 1 < T) stage_half(Bp, K, (t + 1) * 64 + 32, nBk1, tid);             \
    BARM(); LGKM0(); MFMA16(4, b0); BARM();                                     \
    _Pragma("unroll") for (int mm = 0; mm < 4; ++mm)                            \
        av[mm] = read_frag(Ak1, wm * 128 + mm * 16 + lc, lk8);                  \
    _Pragma("unroll") for (int nn = 0; nn < 4; ++nn)                            \
        b1[nn] = read_frag(Bk1, wn * 64 + nn * 16 + lc, lk8);                   \
    if (t + 2 < T) stage_half(Ap, K, (t + 2) * 64, cAk0, tid);                  \
    BARM(); LGKM0(); MFMA16(0, b1); BARM();                                     \
    _Pragma("unroll") for (int mm = 0; mm < 4; ++mm)                            \
        av[mm] = read_frag(Ak1, wm * 128 + (4 + mm) * 16 + lc, lk8);            \
    if (t + 2 < T) { stage_half(Bp, K, (t + 2) * 64, cBk0, tid); VMCNT(4); }    \
    else { VMCNT(0); }                                                          \
    BARM(); LGKM0(); MFMA16(4, b1); BARM();                                     \
  }

// Shared epilogue: acc -> LDS (row-XOR swizzle) -> coalesced dwordx4 stores
#define GEMM_EPILOGUE_STORE(CPTR)                                               \
  unsigned short* eps = &lds[0][0][0][0][0];                                    \
  float bv[4];                                                                  \
  _Pragma("unroll") for (int nn = 0; nn < 4; ++nn)                              \
      bv[nn] = bias[bn * 256 + wn * 64 + nn * 16 + lc];                         \
  _Pragma("unroll") for (int r = 0; r < 2; ++r) {                               \
    if (wm == r) {                                                              \
      _Pragma("unroll") for (int mm = 0; mm < 8; ++mm) {                        \
        _Pragma("unroll") for (int nn = 0; nn < 4; ++nn) {                      \
          int lcol = wn * 64 + nn * 16 + lc;                                    \
          _Pragma("unroll") for (int j = 0; j < 4; ++j) {                       \
            int lrow = mm * 16 + (l >> 4) * 4 + j;                              \
            float v = fmaxf(acc[mm][nn][j] + bv[nn], 0.0f);                     \
            eps[lrow * 256 + (lcol ^ (((lrow >> 2) & 3) << 4))] = f2bf(v);      \
          }                                                                     \
        }                                                                       \
      }                                                                         \
    }                                                                           \
    BARM();                                                                     \
    _Pragma("unroll") for (int it = 0; it < 8; ++it) {                          \
      int flat = it * 512 + tid;                                                \
      int lrow = flat >> 5, cb = flat & 31;                                     \
      int ce = (cb * 8) ^ (((lrow >> 2) & 3) << 4);                             \
      uint4 v = *(const uint4*)&eps[lrow * 256 + ce];                           \
      *(uint4*)&(CPTR)[(size_t)(bm * 256 + r * 128 + lrow) * N + bn * 256 + cb * 8] = v; \
    }                                                                           \
    BARM();                                                                     \
  }

__global__ __launch_bounds__(512, 2) void gemm256(
    const unsigned short* __restrict__ A,   // [M][K] bf16
    const unsigned short* __restrict__ Bt,  // [N][K] bf16
    const float* __restrict__ bias,         // [N] f32
    unsigned short* __restrict__ C,         // [M][N] bf16
    int N, int K) {
  __shared__ alignas(16) unsigned short lds[2][2][2][256][32];   // 128 KiB
  GEMM_PREAMBLE_AND_KLOOP();
  GEMM_EPILOGUE_STORE(C);
}

// L0: same 8-phase schedule, but A = x in f32, converted in-flight (fuses cvt_x).
// Reg-stage: issue float4 loads at ph0/ph2, commit (cvt_pk + ds_write_b128,
// linear dest, same layout as gld_lds) at ph0/ph3 behind counted VMCNT(6).
// Per-tile VM order: [rA0:4][Bk0:2][rA1:4][Bk1:2][rA0':4][Bk0':2] ->
// ph0 VMCNT(6) retires exactly rA0; ph3 VMCNT(6) retires {Bk0,rA1,Bk1} =
// tile t+1 fully certified; 6 outstanding invariant restored (T4: never 0).
__global__ __launch_bounds__(512, 2) void gemm_l0(
    const float* __restrict__ X,            // [Mglobal][K] f32
    const unsigned short* __restrict__ Bt,  // [N][K] bf16
    const float* __restrict__ bias,         // [N] f32
    unsigned short* __restrict__ C,         // [Mchunk][N] bf16
    int N, int K, int row0, int Nn) {
  __shared__ alignas(16) unsigned short lds[2][2][2][256][32];   // 128 KiB
  const int tid = threadIdx.x;
  const int w = tid >> 6, l = tid & 63;
  const int wm = w >> 2, wn = w & 3;
  const int lc = l & 15, lk8 = (l >> 4) * 8;
  const int nbn = N >> 8;
  const int nwg = gridDim.x;
  const int q = nwg >> 3, rr = nwg & 7;
  const int xcd = blockIdx.x & 7, ib = blockIdx.x >> 3;
  const int bswz = (xcd < rr ? xcd * (q + 1) : rr * (q + 1) + (xcd - rr) * q) + ib;
  const int bm = bswz / nbn, bn = bswz - bm * nbn;

  const float* xp = X + (size_t)(row0 + bm * 256) * K;
  const int lim = Nn - (row0 + bm * 256);   // rows >= lim are pad (zero)
  const unsigned short* Bp = Bt + (size_t)bn * 256 * K;
  const int T = K >> 6;

  f32x4 acc[8][4] = {};
  float4 rA0[4], rA1[4];

  // prologue: tile0 A (f32->reg), B via gld; commit tile0; prefetch tile1 k0
  issue_a(xp, K, 0, tid, lim, rA0);
  issue_a(xp, K, 32, tid, lim, rA1);
  stage_half(Bp, K, 0, &lds[0][1][0][0][0], tid);
  stage_half(Bp, K, 32, &lds[0][1][1][0][0], tid);
  VMCNT(4);                                   // drain the 8 f32 loads, keep 4 B-glds
  commit_a(rA0, &lds[0][0][0][0][0], tid, lim);
  commit_a(rA1, &lds[0][0][1][0][0], tid, lim);
  if (T > 1) {
    issue_a(xp, K, 64, tid, lim, rA0);        // tile1 k0
    stage_half(Bp, K, 64, &lds[1][1][0][0][0], tid);
  }
  VMCNT(6);                                   // drain tile0 B-glds
  LGKM0();                                    // ds_writes visible before barrier
  BARM();

  for (int t = 0; t < T; ++t) {
    const int s = t & 1;
    const unsigned short* Ak0 = &lds[s][0][0][0][0];
    const unsigned short* Ak1 = &lds[s][0][1][0][0];
    const unsigned short* Bk0 = &lds[s][1][0][0][0];
    const unsigned short* Bk1 = &lds[s][1][1][0][0];
    bf16x8 av[4], b0[4], b1[4];

    // ---- ph0 ----
#pragma unroll
    for (int mm = 0; mm < 4; ++mm) av[mm] = read_frag(Ak0, wm * 128 + mm * 16 + lc, lk8);
#pragma unroll
    for (int nn = 0; nn < 4; ++nn) b0[nn] = read_frag(Bk0, wn * 64 + nn * 16 + lc, lk8);
    if (t + 1 < T) issue_a(xp, K, (t + 1) * 64 + 32, tid, lim, rA1);
    if (t + 2 < T) { VMCNT(6); } else { VMCNT(0); }
    if (t + 1 < T) commit_a(rA0, &lds[s ^ 1][0][0][0][0], tid, lim);   // A(t+1)k0
    BARM(); LGKM0(); MFMA16(0, b0); BARM();

    // ---- ph1 ----
#pragma unroll
    for (int mm = 0; mm < 4; ++mm) av[mm] = read_frag(Ak0, wm * 128 + (4 + mm) * 16 + lc, lk8);
    if (t + 1 < T) stage_half(Bp, K, (t + 1) * 64 + 32, &lds[s ^ 1][1][1][0][0], tid);
    BARM(); LGKM0(); MFMA16(4, b0); BARM();

    // ---- ph2 ----
#pragma unroll
    for (int mm = 0; mm < 4; ++mm) av[mm] = read_frag(Ak1, wm * 128 + mm * 16 + lc, lk8);
#pragma unroll
    for (int nn = 0; nn < 4; ++nn) b1[nn] = read_frag(Bk1, wn * 64 + nn * 16 + lc, lk8);
    if (t + 2 < T) issue_a(xp, K, (t + 2) * 64, tid, lim, rA0);
    BARM(); LGKM0(); MFMA16(0, b1); BARM();

    // ---- ph3 ----
#pragma unroll
    for (int mm = 0; mm < 4; ++mm) av[mm] = read_frag(Ak1, wm * 128 + (4 + mm) * 16 + lc, lk8);
    if (t + 2 < T) stage_half(Bp, K, (t + 2) * 64, &lds[s][1][0][0][0], tid);
    if (t + 2 < T) { VMCNT(6); } else { VMCNT(0); }
    if (t + 1 < T) commit_a(rA1, &lds[s ^ 1][0][1][0][0], tid, lim);   // A(t+1)k1
    BARM(); LGKM0(); MFMA16(4, b1); BARM();
  }

  GEMM_EPILOGUE_STORE(C);
}

// Last layer: identical K-loop, segment-sum relu'd outputs per graph via
// atomicAdd into part[G][N] (batch sorted; pad rows -> sentinel -1).
__global__ __launch_bounds__(512, 2) void gemm_pool(
    const unsigned short* __restrict__ A,   // [M][K] bf16 (chunk base)
    const unsigned short* __restrict__ Bt,  // [N][K] bf16
    const float* __restrict__ bias,         // [N] f32
    const int* __restrict__ batch,          // [Nn] sorted graph ids (global)
    float* __restrict__ part,               // [G][N] f32 accumulators
    int N, int K, int row0, int Nn) {       // row0 = chunk offset in global rows
  __shared__ alignas(16) unsigned short lds[2][2][2][256][32];   // 128 KiB
  GEMM_PREAMBLE_AND_KLOOP();

  unsigned short* eps = &lds[0][0][0][0][0];
  int* batchLS = (int*)&lds[1][0][0][0][0];   // slot 1 is free post-loop
  if (tid < 256) {
    int grow = row0 + bm * 256 + tid;
    batchLS[tid] = (grow < Nn) ? batch[grow] : -1;
  }
  float bv[4];
#pragma unroll
  for (int nn = 0; nn < 4; ++nn) bv[nn] = bias[bn * 256 + wn * 64 + nn * 16 + lc];

#pragma unroll
  for (int r = 0; r < 2; ++r) {
    if (wm == r) {
#pragma unroll
      for (int mm = 0; mm < 8; ++mm) {
#pragma unroll
        for (int nn = 0; nn < 4; ++nn) {
          int lcol = wn * 64 + nn * 16 + lc;
#pragma unroll
          for (int j = 0; j < 4; ++j) {
            int lrow = mm * 16 + (l >> 4) * 4 + j;
            float v = fmaxf(acc[mm][nn][j] + bv[nn], 0.0f);
            eps[lrow * 256 + (lcol ^ (((lrow >> 2) & 3) << 4))] = f2bf(v);
          }
        }
      }
    }
    BARM();
    {
      int col = tid & 255;
      int half = tid >> 8;
      int gcur = -2;
      float run = 0.f;
      int gcolbase = bn * 256 + col;
      for (int i = 0; i < 64; ++i) {
        int lr = half * 64 + i;
        int g = batchLS[r * 128 + lr];
        if (g != gcur) {
          if (gcur >= 0) atomicAdd(&part[(size_t)gcur * N + gcolbase], run);
          gcur = g; run = 0.f;
        }
        run += bf2f(eps[lr * 256 + (col ^ (((lr >> 2) & 3) << 4))]);
      }
      if (gcur >= 0) atomicAdd(&part[(size_t)gcur * N + gcolbase], run);
    }
    BARM();
  }
}

// ---------------- pool finalize ----------------
__global__ void zero_part(float* __restrict__ part, int n) {
  int i = blockIdx.x * blockDim.x + threadIdx.x;
  if (i < n) part[i] = 0.f;
}

__global__ void pool_div(const float* __restrict__ part, const int* __restrict__ batch,
                         float* __restrict__ out, int n, int D, int G) {
  int idx = blockIdx.x * blockDim.x + threadIdx.x;
  if (idx >= G * D) return;
  int g = idx / D;
  int lo, hi;
  { int a = 0, b = n; while (a < b) { int m = (a + b) >> 1; if (batch[m] < g) a = m + 1; else b = m; } lo = a; }
  { int a = lo, b = n; while (a < b) { int m = (a + b) >> 1; if (batch[m] < g + 1) a = m + 1; else b = m; } hi = a; }
  out[idx] = part[idx] / (float)(hi - lo);
}

// ---------------- launcher ----------------
static inline size_t align256(size_t x) { return (x + 255) & ~(size_t)255; }

extern "C" void kernel_launch(void* const* d_in, const int* in_sizes, int n_in,
                              void* d_out, int out_size, void* d_ws, size_t ws_size,
                              hipStream_t stream) {
  const float* x = (const float*)d_in[0];
  // d_in[1] = edge_index (unused by the math)
  const int* batch = (const int*)d_in[2];
  const float* W0 = (const float*)d_in[3];
  const float* b0 = (const float*)d_in[4];
  const float* W1 = (const float*)d_in[5];
  const float* b1 = (const float*)d_in[6];
  const float* W2 = (const float*)d_in[7];
  const float* b2 = (const float*)d_in[8];
  float* out = (float*)d_out;

  const int Nn = in_sizes[2];                 // 100000 nodes
  const int DIN = 512, DH = 1024, DOUT = 512;
  const int G = out_size / DOUT;              // 128
  const int Mpad = ((Nn + 255) / 256) * 256;  // 100096

  // workspace layout (xb and h2 eliminated)
  uint8_t* p = (uint8_t*)d_ws;
  unsigned short* W0t = (unsigned short*)p; p += align256((size_t)DH * DIN * 2);
  unsigned short* W1t = (unsigned short*)p; p += align256((size_t)DH * DH * 2);
  unsigned short* W2t = (unsigned short*)p; p += align256((size_t)DOUT * DH * 2);
  float* part         = (float*)p;          p += align256((size_t)G * DOUT * 4);
  size_t used = (size_t)(p - (uint8_t*)d_ws);
  size_t avail = ws_size > used ? ws_size - used : 0;
  size_t per_row = (size_t)(DH + DH) * 2;             // h0 + h1 bytes per row
  long long chl = (long long)(avail / per_row);
  chl = (chl / 256) * 256;
  int CH = (int)(chl < 256 ? 256 : chl);
  if (CH > Mpad) CH = Mpad;
  unsigned short* h0 = (unsigned short*)p; p += align256((size_t)CH * DH * 2);
  unsigned short* h1 = (unsigned short*)p; p += align256((size_t)CH * DH * 2);

  // 0) zero the pooling accumulators
  zero_part<<<dim3((G * DOUT + 255) / 256), 256, 0, stream>>>(part, G * DOUT);

  // 1) weights: transpose + convert to bf16 [N][K]
  transpose_w<<<dim3((DIN / 32) * (DH / 32)), 256, 0, stream>>>(W0, W0t, DIN, DH);
  transpose_w<<<dim3((DH / 32) * (DH / 32)), 256, 0, stream>>>(W1, W1t, DH, DH);
  transpose_w<<<dim3((DH / 32) * (DOUT / 32)), 256, 0, stream>>>(W2, W2t, DH, DOUT);

  // 2) chunked 3-layer MLP; L0 fuses the f32->bf16 conversion, L2 fuses the pool
  for (int off = 0; off < Mpad; off += CH) {
    int rows = Mpad - off; if (rows > CH) rows = CH;

    gemm_l0<<<dim3((rows / 256) * (DH / 256)), 512, 0, stream>>>(
        x, W0t, b0, h0, DH, DIN, off, Nn);
    gemm256<<<dim3((rows / 256) * (DH / 256)), 512, 0, stream>>>(h0, W1t, b1, h1, DH, DH);
    gemm_pool<<<dim3((rows / 256) * (DOUT / 256)), 512, 0, stream>>>(
        h1, W2t, b2, batch, part, DOUT, DH, off, Nn);
  }

  // 3) finalize: mean = sum / count
  pool_div<<<dim3((G * DOUT + 255) / 256), 256, 0, stream>>>(part, batch, out, Nn, DOUT, G);
}

// Round 10
// 676.264 us; speedup vs baseline: 1.0256x; 1.0256x over previous
//
#include <hip/hip_runtime.h>
#include <cstdint>
#include <cstddef>

// ---------------- types / helpers ----------------
typedef __bf16 bf16x8 __attribute__((ext_vector_type(8)));
typedef float f32x4 __attribute__((ext_vector_type(4)));

__device__ __forceinline__ unsigned short f2bf(float f) {
  unsigned u = __float_as_uint(f);
  u += 0x7fffu + ((u >> 16) & 1u);   // RNE
  return (unsigned short)(u >> 16);
}
__device__ __forceinline__ float bf2f(unsigned short s) {
  return __uint_as_float(((unsigned)s) << 16);
}

// async global->LDS, 16B per lane, linear dest (wave-uniform base + lane*16)
__device__ __forceinline__ void gld_lds16(const void* g, void* l) {
  __builtin_amdgcn_global_load_lds(
      (const __attribute__((address_space(1))) void*)g,
      (__attribute__((address_space(3))) void*)l, 16, 0, 0);
}

#define BARM() do { __builtin_amdgcn_s_barrier(); asm volatile("" ::: "memory"); } while (0)
#define VMCNT(n) asm volatile("s_waitcnt vmcnt(" #n ")" ::: "memory")
#define LGKM0()  do { asm volatile("s_waitcnt lgkmcnt(0)" ::: "memory"); \
                      __builtin_amdgcn_sched_barrier(0); } while (0)

// ---------------- transpose + convert W [K][N] f32 -> Wt [N][K] bf16 ----------------
__global__ void transpose_w(const float* __restrict__ w, unsigned short* __restrict__ wt,
                            int K, int N) {
  __shared__ float tile[32][33];
  int nt = N >> 5;
  int bx = blockIdx.x % nt;   // n tile
  int by = blockIdx.x / nt;   // k tile
  int tx = threadIdx.x & 31, ty = threadIdx.x >> 5;  // 32x8
#pragma unroll
  for (int r = 0; r < 32; r += 8)
    tile[ty + r][tx] = w[(size_t)(by * 32 + ty + r) * N + bx * 32 + tx];
  __syncthreads();
#pragma unroll
  for (int r = 0; r < 32; r += 8)
    wt[(size_t)(bx * 32 + ty + r) * K + by * 32 + tx] = f2bf(tile[tx][ty + r]);
}

// ---------------- x f32 -> bf16 (chunk, zero-pad rows >= nvalid) ----------------
// Standalone on purpose (round-9 lesson): fusing the cvt into L0 re-reads x in
// f32 once per bn-block (4x the bytes); a one-shot pass converts once and runs
// at the HBM ceiling (~6.0 TB/s measured).
__global__ void cvt_x(const float* __restrict__ x, unsigned short* __restrict__ xb,
                      int rows, int nvalid, int D) {
  size_t total = (size_t)rows * D / 8;
  for (size_t i = (size_t)blockIdx.x * blockDim.x + threadIdx.x; i < total;
       i += (size_t)gridDim.x * blockDim.x) {
    size_t e = i * 8;
    int row = (int)(e / (size_t)D);
    uint4 ov;
    if (row < nvalid) {
      const float4* s = (const float4*)(x + e);
      float4 v0 = s[0], v1 = s[1];
      ov.x = (unsigned)f2bf(v0.x) | ((unsigned)f2bf(v0.y) << 16);
      ov.y = (unsigned)f2bf(v0.z) | ((unsigned)f2bf(v0.w) << 16);
      ov.z = (unsigned)f2bf(v1.x) | ((unsigned)f2bf(v1.y) << 16);
      ov.w = (unsigned)f2bf(v1.z) | ((unsigned)f2bf(v1.w) << 16);
    } else {
      ov.x = ov.y = ov.z = ov.w = 0u;
    }
    *(uint4*)(xb + e) = ov;
  }
}

// ---------------- 256x256 8-phase GEMM core (round-4 proven) ----------------
__device__ __forceinline__ bf16x8 read_frag(const unsigned short* region, int row, int kel) {
  int ke = kel ^ (((row >> 1) & 3) << 3);
  return *(const bf16x8*)(region + row * 32 + ke);
}

__device__ __forceinline__ void stage_half(const unsigned short* gpanel, int K, int kofs,
                                           unsigned short* region, int tid) {
#pragma unroll
  for (int r = 0; r < 2; ++r) {
    int row = r * 128 + (tid >> 2);
    int ke = ((tid & 3) * 8) ^ (((row >> 1) & 3) << 3);  // inverse-swizzled source
    gld_lds16(gpanel + (size_t)row * K + kofs + ke, region + r * 4096 + tid * 8);
  }
}

#define MFMA16(MB, BV)                                                          \
  do {                                                                          \
    __builtin_amdgcn_s_setprio(1);                                              \
    _Pragma("unroll") for (int mm = 0; mm < 4; ++mm) {                          \
      _Pragma("unroll") for (int nn = 0; nn < 4; ++nn)                          \
        acc[(MB) + mm][nn] = __builtin_amdgcn_mfma_f32_16x16x32_bf16(           \
            av[mm], BV[nn], acc[(MB) + mm][nn], 0, 0, 0);                       \
    }                                                                           \
    __builtin_amdgcn_s_setprio(0);                                              \
  } while (0)

// Shared K-loop body for both gemm variants. Defines acc[8][4] and runs the
// 8-phase schedule; caller provides epilogue.
#define GEMM_PREAMBLE_AND_KLOOP()                                               \
  const int tid = threadIdx.x;                                                  \
  const int w = tid >> 6, l = tid & 63;                                         \
  const int wm = w >> 2, wn = w & 3;                                            \
  const int lc = l & 15, lk8 = (l >> 4) * 8;                                    \
  const int nbn = N >> 8;                                                       \
  const int nwg = gridDim.x;                                                    \
  const int q = nwg >> 3, rr = nwg & 7;                                         \
  const int xcd = blockIdx.x & 7, ib = blockIdx.x >> 3;                         \
  const int bswz = (xcd < rr ? xcd * (q + 1) : rr * (q + 1) + (xcd - rr) * q) + ib; \
  const int bm = bswz / nbn, bn = bswz - bm * nbn;                              \
  const unsigned short* Ap = A + (size_t)bm * 256 * K;                          \
  const unsigned short* Bp = Bt + (size_t)bn * 256 * K;                         \
  const int T = K >> 6;                                                         \
  f32x4 acc[8][4] = {};                                                         \
  stage_half(Ap, K, 0, &lds[0][0][0][0][0], tid);                               \
  stage_half(Bp, K, 0, &lds[0][1][0][0][0], tid);                               \
  stage_half(Ap, K, 32, &lds[0][0][1][0][0], tid);                              \
  stage_half(Bp, K, 32, &lds[0][1][1][0][0], tid);                              \
  stage_half(Ap, K, 64, &lds[1][0][0][0][0], tid);                              \
  stage_half(Bp, K, 64, &lds[1][1][0][0][0], tid);                              \
  VMCNT(4);                                                                     \
  BARM();                                                                       \
  for (int t = 0; t < T; ++t) {                                                 \
    const int s = t & 1;                                                        \
    const unsigned short* Ak0 = &lds[s][0][0][0][0];                            \
    const unsigned short* Ak1 = &lds[s][0][1][0][0];                            \
    const unsigned short* Bk0 = &lds[s][1][0][0][0];                            \
    const unsigned short* Bk1 = &lds[s][1][1][0][0];                            \
    unsigned short* nAk1 = &lds[s ^ 1][0][1][0][0];                             \
    unsigned short* nBk1 = &lds[s ^ 1][1][1][0][0];                             \
    unsigned short* cAk0 = &lds[s][0][0][0][0];                                 \
    unsigned short* cBk0 = &lds[s][1][0][0][0];                                 \
    bf16x8 av[4], b0[4], b1[4];                                                 \
    _Pragma("unroll") for (int mm = 0; mm < 4; ++mm)                            \
        av[mm] = read_frag(Ak0, wm * 128 + mm * 16 + lc, lk8);                  \
    _Pragma("unroll") for (int nn = 0; nn < 4; ++nn)                            \
        b0[nn] = read_frag(Bk0, wn * 64 + nn * 16 + lc, lk8);                   \
    if (t + 1 < T) stage_half(Ap, K, (t + 1) * 64 + 32, nAk1, tid);             \
    BARM(); LGKM0(); MFMA16(0, b0); BARM();                                     \
    _Pragma("unroll") for (int mm = 0; mm < 4; ++mm)                            \
        av[mm] = read_frag(Ak0, wm * 128 + (4 + mm) * 16 + lc, lk8);            \
    if (t + 1 < T) stage_half(Bp, K, (t + 1) * 64 + 32, nBk1, tid);             \
    BARM(); LGKM0(); MFMA16(4, b0); BARM();                                     \
    _Pragma("unroll") for (int mm = 0; mm < 4; ++mm)                            \
        av[mm] = read_frag(Ak1, wm * 128 + mm * 16 + lc, lk8);                  \
    _Pragma("unroll") for (int nn = 0; nn < 4; ++nn)                            \
        b1[nn] = read_frag(Bk1, wn * 64 + nn * 16 + lc, lk8);                   \
    if (t + 2 < T) stage_half(Ap, K, (t + 2) * 64, cAk0, tid);                  \
    BARM(); LGKM0(); MFMA16(0, b1); BARM();                                     \
    _Pragma("unroll") for (int mm = 0; mm < 4; ++mm)                            \
        av[mm] = read_frag(Ak1, wm * 128 + (4 + mm) * 16 + lc, lk8);            \
    if (t + 2 < T) { stage_half(Bp, K, (t + 2) * 64, cBk0, tid); VMCNT(4); }    \
    else { VMCNT(0); }                                                          \
    BARM(); LGKM0(); MFMA16(4, b1); BARM();                                     \
  }

__global__ __launch_bounds__(512, 2) void gemm256(
    const unsigned short* __restrict__ A,   // [M][K] bf16
    const unsigned short* __restrict__ Bt,  // [N][K] bf16
    const float* __restrict__ bias,         // [N] f32
    unsigned short* __restrict__ C,         // [M][N] bf16
    int N, int K) {
  __shared__ alignas(16) unsigned short lds[2][2][2][256][32];   // 128 KiB
  GEMM_PREAMBLE_AND_KLOOP();

  // ---- epilogue: acc -> LDS (row-XOR swizzle) -> coalesced dwordx4 stores ----
  unsigned short* eps = &lds[0][0][0][0][0];
  float bv[4];
#pragma unroll
  for (int nn = 0; nn < 4; ++nn) bv[nn] = bias[bn * 256 + wn * 64 + nn * 16 + lc];

#pragma unroll
  for (int r = 0; r < 2; ++r) {
    if (wm == r) {
#pragma unroll
      for (int mm = 0; mm < 8; ++mm) {
#pragma unroll
        for (int nn = 0; nn < 4; ++nn) {
          int lcol = wn * 64 + nn * 16 + lc;
#pragma unroll
          for (int j = 0; j < 4; ++j) {
            int lrow = mm * 16 + (l >> 4) * 4 + j;
            float v = fmaxf(acc[mm][nn][j] + bv[nn], 0.0f);
            eps[lrow * 256 + (lcol ^ (((lrow >> 2) & 3) << 4))] = f2bf(v);
          }
        }
      }
    }
    BARM();
#pragma unroll
    for (int it = 0; it < 8; ++it) {
      int flat = it * 512 + tid;          // 4096 = 128 rows x 32 col-granules
      int lrow = flat >> 5, cb = flat & 31;
      int ce = (cb * 8) ^ (((lrow >> 2) & 3) << 4);
      uint4 v = *(const uint4*)&eps[lrow * 256 + ce];
      *(uint4*)&C[(size_t)(bm * 256 + r * 128 + lrow) * N + bn * 256 + cb * 8] = v;
    }
    BARM();
  }
}

// Last layer: identical K-loop, but instead of writing C, segment-sum the
// relu'd outputs per graph (batch sorted; pad rows -> sentinel -1) and
// atomicAdd into part[G][N]. Skips the h2 round-trip and pool_partial.
__global__ __launch_bounds__(512, 2) void gemm_pool(
    const unsigned short* __restrict__ A,   // [M][K] bf16 (chunk base)
    const unsigned short* __restrict__ Bt,  // [N][K] bf16
    const float* __restrict__ bias,         // [N] f32
    const int* __restrict__ batch,          // [Nn] sorted graph ids (global)
    float* __restrict__ part,               // [G][N] f32 accumulators
    int N, int K, int row0, int Nn) {       // row0 = chunk offset in global rows
  __shared__ alignas(16) unsigned short lds[2][2][2][256][32];   // 128 KiB
  GEMM_PREAMBLE_AND_KLOOP();

  unsigned short* eps = &lds[0][0][0][0][0];
  int* batchLS = (int*)&lds[1][0][0][0][0];   // slot 1 is free post-loop
  // stage batch ids for this block's 256 rows (global rows row0+bm*256+i)
  if (tid < 256) {
    int grow = row0 + bm * 256 + tid;
    batchLS[tid] = (grow < Nn) ? batch[grow] : -1;
  }
  float bv[4];
#pragma unroll
  for (int nn = 0; nn < 4; ++nn) bv[nn] = bias[bn * 256 + wn * 64 + nn * 16 + lc];

#pragma unroll
  for (int r = 0; r < 2; ++r) {
    if (wm == r) {
#pragma unroll
      for (int mm = 0; mm < 8; ++mm) {
#pragma unroll
        for (int nn = 0; nn < 4; ++nn) {
          int lcol = wn * 64 + nn * 16 + lc;
#pragma unroll
          for (int j = 0; j < 4; ++j) {
            int lrow = mm * 16 + (l >> 4) * 4 + j;
            float v = fmaxf(acc[mm][nn][j] + bv[nn], 0.0f);
            eps[lrow * 256 + (lcol ^ (((lrow >> 2) & 3) << 4))] = f2bf(v);
          }
        }
      }
    }
    BARM();
    // column scan: thread -> (col = tid&255, rows half*64..half*64+63)
    {
      int col = tid & 255;
      int half = tid >> 8;
      int gcur = -2;
      float run = 0.f;
      int gcolbase = bn * 256 + col;
      for (int i = 0; i < 64; ++i) {
        int lr = half * 64 + i;
        int g = batchLS[r * 128 + lr];
        if (g != gcur) {
          if (gcur >= 0) atomicAdd(&part[(size_t)gcur * N + gcolbase], run);
          gcur = g; run = 0.f;
        }
        run += bf2f(eps[lr * 256 + (col ^ (((lr >> 2) & 3) << 4))]);
      }
      if (gcur >= 0) atomicAdd(&part[(size_t)gcur * N + gcolbase], run);
    }
    BARM();
  }
}

// ---------------- pool finalize ----------------
__global__ void zero_part(float* __restrict__ part, int n) {
  int i = blockIdx.x * blockDim.x + threadIdx.x;
  if (i < n) part[i] = 0.f;
}

__global__ void pool_div(const float* __restrict__ part, const int* __restrict__ batch,
                         float* __restrict__ out, int n, int D, int G) {
  int idx = blockIdx.x * blockDim.x + threadIdx.x;
  if (idx >= G * D) return;
  int g = idx / D;
  int lo, hi;
  { int a = 0, b = n; while (a < b) { int m = (a + b) >> 1; if (batch[m] < g) a = m + 1; else b = m; } lo = a; }
  { int a = lo, b = n; while (a < b) { int m = (a + b) >> 1; if (batch[m] < g + 1) a = m + 1; else b = m; } hi = a; }
  out[idx] = part[idx] / (float)(hi - lo);
}

// ---------------- launcher ----------------
static inline size_t align256(size_t x) { return (x + 255) & ~(size_t)255; }

extern "C" void kernel_launch(void* const* d_in, const int* in_sizes, int n_in,
                              void* d_out, int out_size, void* d_ws, size_t ws_size,
                              hipStream_t stream) {
  const float* x = (const float*)d_in[0];
  // d_in[1] = edge_index (unused by the math)
  const int* batch = (const int*)d_in[2];
  const float* W0 = (const float*)d_in[3];
  const float* b0 = (const float*)d_in[4];
  const float* W1 = (const float*)d_in[5];
  const float* b1 = (const float*)d_in[6];
  const float* W2 = (const float*)d_in[7];
  const float* b2 = (const float*)d_in[8];
  float* out = (float*)d_out;

  const int Nn = in_sizes[2];                 // 100000 nodes
  const int DIN = 512, DH = 1024, DOUT = 512;
  const int G = out_size / DOUT;              // 128
  const int Mpad = ((Nn + 255) / 256) * 256;  // 100096

  // workspace layout (h2 eliminated)
  uint8_t* p = (uint8_t*)d_ws;
  unsigned short* W0t = (unsigned short*)p; p += align256((size_t)DH * DIN * 2);
  unsigned short* W1t = (unsigned short*)p; p += align256((size_t)DH * DH * 2);
  unsigned short* W2t = (unsigned short*)p; p += align256((size_t)DOUT * DH * 2);
  float* part         = (float*)p;          p += align256((size_t)G * DOUT * 4);
  size_t used = (size_t)(p - (uint8_t*)d_ws);
  size_t avail = ws_size > used ? ws_size - used : 0;
  size_t per_row = (size_t)(DIN + DH + DH) * 2;       // xb + h0 + h1 bytes per row
  long long chl = (long long)(avail / per_row);
  chl = (chl / 256) * 256;
  int CH = (int)(chl < 256 ? 256 : chl);
  if (CH > Mpad) CH = Mpad;
  unsigned short* xb = (unsigned short*)p; p += align256((size_t)CH * DIN * 2);
  unsigned short* h0 = (unsigned short*)p; p += align256((size_t)CH * DH * 2);
  unsigned short* h1 = (unsigned short*)p; p += align256((size_t)CH * DH * 2);

  // 0) zero the pooling accumulators
  zero_part<<<dim3((G * DOUT + 255) / 256), 256, 0, stream>>>(part, G * DOUT);

  // 1) weights: transpose + convert to bf16 [N][K]
  transpose_w<<<dim3((DIN / 32) * (DH / 32)), 256, 0, stream>>>(W0, W0t, DIN, DH);
  transpose_w<<<dim3((DH / 32) * (DH / 32)), 256, 0, stream>>>(W1, W1t, DH, DH);
  transpose_w<<<dim3((DH / 32) * (DOUT / 32)), 256, 0, stream>>>(W2, W2t, DH, DOUT);

  // 2) chunked 3-layer MLP (single chunk when ws allows); L2 fuses the pool
  for (int off = 0; off < Mpad; off += CH) {
    int rows = Mpad - off; if (rows > CH) rows = CH;
    int nvalid = Nn - off;
    size_t cvt_threads = (size_t)rows * DIN / 8;
    int cvt_blocks = (int)((cvt_threads + 255) / 256);
    if (cvt_blocks > 2048) cvt_blocks = 2048;
    cvt_x<<<dim3(cvt_blocks), 256, 0, stream>>>(x + (size_t)off * DIN, xb, rows, nvalid, DIN);

    gemm256<<<dim3((rows / 256) * (DH / 256)), 512, 0, stream>>>(xb, W0t, b0, h0, DH, DIN);
    gemm256<<<dim3((rows / 256) * (DH / 256)), 512, 0, stream>>>(h0, W1t, b1, h1, DH, DH);
    gemm_pool<<<dim3((rows / 256) * (DOUT / 256)), 512, 0, stream>>>(
        h1, W2t, b2, batch, part, DOUT, DH, off, Nn);
  }

  // 3) finalize: mean = sum / count
  pool_div<<<dim3((G * DOUT + 255) / 256), 256, 0, stream>>>(part, batch, out, Nn, DOUT, G);
}

// Round 11
// 659.293 us; speedup vs baseline: 1.0520x; 1.0257x over previous
//
#include <hip/hip_runtime.h>
#include <cstdint>
#include <cstddef>

// ---------------- types / helpers ----------------
typedef __bf16 bf16x8 __attribute__((ext_vector_type(8)));
typedef float f32x4 __attribute__((ext_vector_type(4)));

__device__ __forceinline__ unsigned short f2bf(float f) {
  unsigned u = __float_as_uint(f);
  u += 0x7fffu + ((u >> 16) & 1u);   // RNE
  return (unsigned short)(u >> 16);
}
__device__ __forceinline__ float bf2f(unsigned short s) {
  return __uint_as_float(((unsigned)s) << 16);
}

// async global->LDS, 16B per lane, linear dest (wave-uniform base + lane*16)
__device__ __forceinline__ void gld_lds16(const void* g, void* l) {
  __builtin_amdgcn_global_load_lds(
      (const __attribute__((address_space(1))) void*)g,
      (__attribute__((address_space(3))) void*)l, 16, 0, 0);
}

#define BARM() do { __builtin_amdgcn_s_barrier(); asm volatile("" ::: "memory"); } while (0)
#define VMCNT(n) asm volatile("s_waitcnt vmcnt(" #n ")" ::: "memory")
#define LGKM0()  do { asm volatile("s_waitcnt lgkmcnt(0)" ::: "memory"); \
                      __builtin_amdgcn_sched_barrier(0); } while (0)

// ---------------- transpose + convert W [K][N] f32 -> Wt [N][K] bf16 ----------------
__global__ void transpose_w(const float* __restrict__ w, unsigned short* __restrict__ wt,
                            int K, int N) {
  __shared__ float tile[32][33];
  int nt = N >> 5;
  int bx = blockIdx.x % nt;   // n tile
  int by = blockIdx.x / nt;   // k tile
  int tx = threadIdx.x & 31, ty = threadIdx.x >> 5;  // 32x8
#pragma unroll
  for (int r = 0; r < 32; r += 8)
    tile[ty + r][tx] = w[(size_t)(by * 32 + ty + r) * N + bx * 32 + tx];
  __syncthreads();
#pragma unroll
  for (int r = 0; r < 32; r += 8)
    wt[(size_t)(bx * 32 + ty + r) * K + by * 32 + tx] = f2bf(tile[tx][ty + r]);
}

// ---------------- x f32 -> bf16 (chunk, zero-pad rows >= nvalid) ----------------
// Standalone on purpose (round-9 lesson): fusing into L0 re-reads x in f32 per
// bn-block (4x bytes); one-shot pass runs at the HBM ceiling (~6.0 TB/s).
__global__ void cvt_x(const float* __restrict__ x, unsigned short* __restrict__ xb,
                      int rows, int nvalid, int D) {
  size_t total = (size_t)rows * D / 8;
  for (size_t i = (size_t)blockIdx.x * blockDim.x + threadIdx.x; i < total;
       i += (size_t)gridDim.x * blockDim.x) {
    size_t e = i * 8;
    int row = (int)(e / (size_t)D);
    uint4 ov;
    if (row < nvalid) {
      const float4* s = (const float4*)(x + e);
      float4 v0 = s[0], v1 = s[1];
      ov.x = (unsigned)f2bf(v0.x) | ((unsigned)f2bf(v0.y) << 16);
      ov.y = (unsigned)f2bf(v0.z) | ((unsigned)f2bf(v0.w) << 16);
      ov.z = (unsigned)f2bf(v1.x) | ((unsigned)f2bf(v1.y) << 16);
      ov.w = (unsigned)f2bf(v1.z) | ((unsigned)f2bf(v1.w) << 16);
    } else {
      ov.x = ov.y = ov.z = ov.w = 0u;
    }
    *(uint4*)(xb + e) = ov;
  }
}

// ---------------- 256x256 8-phase GEMM, 16 waves (4Mx4N), per-wave 64x64 ----------------
// Round-11 change vs r4/r8: 1024 threads instead of 512. Same 128 KiB LDS,
// same barrier/vmcnt skeleton, but 4 waves/SIMD instead of 2 -> TLP to cover
// each wave's lgkm-wait + MFMA-blocked window (the measured wall: 6150 cyc/
// K64-group where MFMA needs 2060 and LDS ~2800 -> latency-bound, not pipes).
// acc shrinks to 64 VGPR/thread. stage_half = 1 gld_lds per wave, so the
// counted-vmcnt constants change 4->2 (same certification proof as r4):
// outstanding at ph3 = [t+1k0 x2][t+1k1 x2][t+2k0 x2]; VMCNT(2) certifies
// tile t+1 fully, leaves t+2 k0 in flight (T4: never 0 mid-loop).
__device__ __forceinline__ bf16x8 read_frag(const unsigned short* region, int row, int kel) {
  int ke = kel ^ (((row >> 1) & 3) << 3);
  return *(const bf16x8*)(region + row * 32 + ke);
}

__device__ __forceinline__ void stage_half(const unsigned short* gpanel, int K, int kofs,
                                           unsigned short* region, int tid) {
  int row = tid >> 2;                                  // 1024 threads -> 256 rows x 4
  int ke = ((tid & 3) * 8) ^ (((row >> 1) & 3) << 3);  // inverse-swizzled source
  gld_lds16(gpanel + (size_t)row * K + kofs + ke, region + tid * 8);
}

#define MFMA8(MB, BV)                                                           \
  do {                                                                          \
    __builtin_amdgcn_s_setprio(1);                                              \
    _Pragma("unroll") for (int mm = 0; mm < 2; ++mm) {                          \
      _Pragma("unroll") for (int nn = 0; nn < 4; ++nn)                          \
        acc[(MB) + mm][nn] = __builtin_amdgcn_mfma_f32_16x16x32_bf16(           \
            av[mm], BV[nn], acc[(MB) + mm][nn], 0, 0, 0);                       \
    }                                                                           \
    __builtin_amdgcn_s_setprio(0);                                              \
  } while (0)

// Shared K-loop body. Defines acc[4][4]; caller provides epilogue.
#define GEMM_PREAMBLE_AND_KLOOP()                                               \
  const int tid = threadIdx.x;                                                  \
  const int w = tid >> 6, l = tid & 63;                                         \
  const int wm = w >> 2, wn = w & 3;                                            \
  const int lc = l & 15, lk8 = (l >> 4) * 8;                                    \
  const int nbn = N >> 8;                                                       \
  const int nwg = gridDim.x;                                                    \
  const int q = nwg >> 3, rr = nwg & 7;                                         \
  const int xcd = blockIdx.x & 7, ib = blockIdx.x >> 3;                         \
  const int bswz = (xcd < rr ? xcd * (q + 1) : rr * (q + 1) + (xcd - rr) * q) + ib; \
  const int bm = bswz / nbn, bn = bswz - bm * nbn;                              \
  const unsigned short* Ap = A + (size_t)bm * 256 * K;                          \
  const unsigned short* Bp = Bt + (size_t)bn * 256 * K;                         \
  const int T = K >> 6;                                                         \
  f32x4 acc[4][4] = {};                                                         \
  stage_half(Ap, K, 0, &lds[0][0][0][0][0], tid);                               \
  stage_half(Bp, K, 0, &lds[0][1][0][0][0], tid);                               \
  stage_half(Ap, K, 32, &lds[0][0][1][0][0], tid);                              \
  stage_half(Bp, K, 32, &lds[0][1][1][0][0], tid);                              \
  stage_half(Ap, K, 64, &lds[1][0][0][0][0], tid);                              \
  stage_half(Bp, K, 64, &lds[1][1][0][0][0], tid);                              \
  VMCNT(2);                                                                     \
  BARM();                                                                       \
  for (int t = 0; t < T; ++t) {                                                 \
    const int s = t & 1;                                                        \
    const unsigned short* Ak0 = &lds[s][0][0][0][0];                            \
    const unsigned short* Ak1 = &lds[s][0][1][0][0];                            \
    const unsigned short* Bk0 = &lds[s][1][0][0][0];                            \
    const unsigned short* Bk1 = &lds[s][1][1][0][0];                            \
    unsigned short* nAk1 = &lds[s ^ 1][0][1][0][0];                             \
    unsigned short* nBk1 = &lds[s ^ 1][1][1][0][0];                             \
    unsigned short* cAk0 = &lds[s][0][0][0][0];                                 \
    unsigned short* cBk0 = &lds[s][1][0][0][0];                                 \
    bf16x8 av[2], b0[4], b1[4];                                                 \
    /* ph0: A mf0-1 k0 + B k0; stage A(t+1)k1 */                                \
    _Pragma("unroll") for (int mm = 0; mm < 2; ++mm)                            \
        av[mm] = read_frag(Ak0, wm * 64 + mm * 16 + lc, lk8);                   \
    _Pragma("unroll") for (int nn = 0; nn < 4; ++nn)                            \
        b0[nn] = read_frag(Bk0, wn * 64 + nn * 16 + lc, lk8);                   \
    if (t + 1 < T) stage_half(Ap, K, (t + 1) * 64 + 32, nAk1, tid);             \
    BARM(); LGKM0(); MFMA8(0, b0); BARM();                                      \
    /* ph1: A mf2-3 k0; stage B(t+1)k1 */                                       \
    _Pragma("unroll") for (int mm = 0; mm < 2; ++mm)                            \
        av[mm] = read_frag(Ak0, wm * 64 + (2 + mm) * 16 + lc, lk8);             \
    if (t + 1 < T) stage_half(Bp, K, (t + 1) * 64 + 32, nBk1, tid);             \
    BARM(); LGKM0(); MFMA8(2, b0); BARM();                                      \
    /* ph2: A mf0-1 k1 + B k1; stage A(t+2)k0 */                                \
    _Pragma("unroll") for (int mm = 0; mm < 2; ++mm)                            \
        av[mm] = read_frag(Ak1, wm * 64 + mm * 16 + lc, lk8);                   \
    _Pragma("unroll") for (int nn = 0; nn < 4; ++nn)                            \
        b1[nn] = read_frag(Bk1, wn * 64 + nn * 16 + lc, lk8);                   \
    if (t + 2 < T) stage_half(Ap, K, (t + 2) * 64, cAk0, tid);                  \
    BARM(); LGKM0(); MFMA8(0, b1); BARM();                                      \
    /* ph3: A mf2-3 k1; stage B(t+2)k0; counted certify */                      \
    _Pragma("unroll") for (int mm = 0; mm < 2; ++mm)                            \
        av[mm] = read_frag(Ak1, wm * 64 + (2 + mm) * 16 + lc, lk8);             \
    if (t + 2 < T) { stage_half(Bp, K, (t + 2) * 64, cBk0, tid); VMCNT(2); }    \
    else { VMCNT(0); }                                                          \
    BARM(); LGKM0(); MFMA8(2, b1); BARM();                                      \
  }

__global__ __launch_bounds__(1024, 1) void gemm256(
    const unsigned short* __restrict__ A,   // [M][K] bf16
    const unsigned short* __restrict__ Bt,  // [N][K] bf16
    const float* __restrict__ bias,         // [N] f32
    unsigned short* __restrict__ C,         // [M][N] bf16
    int N, int K) {
  __shared__ alignas(16) unsigned short lds[2][2][2][256][32];   // 128 KiB
  GEMM_PREAMBLE_AND_KLOOP();

  // ---- epilogue: acc -> LDS (row-XOR swizzle) -> coalesced dwordx4 stores ----
  unsigned short* eps = &lds[0][0][0][0][0];   // [128][256] bf16 per round
  float bv[4];
#pragma unroll
  for (int nn = 0; nn < 4; ++nn) bv[nn] = bias[bn * 256 + wn * 64 + nn * 16 + lc];

#pragma unroll
  for (int r = 0; r < 2; ++r) {
    if ((wm >> 1) == r) {                      // waves wm=2r,2r+1 own rows r*128..+127
#pragma unroll
      for (int mm = 0; mm < 4; ++mm) {
#pragma unroll
        for (int nn = 0; nn < 4; ++nn) {
          int lcol = wn * 64 + nn * 16 + lc;
#pragma unroll
          for (int j = 0; j < 4; ++j) {
            int lrow = (wm & 1) * 64 + mm * 16 + (l >> 4) * 4 + j;
            float v = fmaxf(acc[mm][nn][j] + bv[nn], 0.0f);
            eps[lrow * 256 + (lcol ^ (((lrow >> 2) & 3) << 4))] = f2bf(v);
          }
        }
      }
    }
    BARM();
#pragma unroll
    for (int it = 0; it < 4; ++it) {
      int flat = it * 1024 + tid;          // 4096 = 128 rows x 32 col-granules
      int lrow = flat >> 5, cb = flat & 31;
      int ce = (cb * 8) ^ (((lrow >> 2) & 3) << 4);
      uint4 v = *(const uint4*)&eps[lrow * 256 + ce];
      *(uint4*)&C[(size_t)(bm * 256 + r * 128 + lrow) * N + bn * 256 + cb * 8] = v;
    }
    BARM();
  }
}

// Last layer: identical K-loop; segment-sum relu'd outputs per graph via
// atomicAdd into part[G][N] (batch sorted; pad rows -> sentinel -1).
__global__ __launch_bounds__(1024, 1) void gemm_pool(
    const unsigned short* __restrict__ A,   // [M][K] bf16 (chunk base)
    const unsigned short* __restrict__ Bt,  // [N][K] bf16
    const float* __restrict__ bias,         // [N] f32
    const int* __restrict__ batch,          // [Nn] sorted graph ids (global)
    float* __restrict__ part,               // [G][N] f32 accumulators
    int N, int K, int row0, int Nn) {       // row0 = chunk offset in global rows
  __shared__ alignas(16) unsigned short lds[2][2][2][256][32];   // 128 KiB
  GEMM_PREAMBLE_AND_KLOOP();

  unsigned short* eps = &lds[0][0][0][0][0];
  int* batchLS = (int*)&lds[1][0][0][0][0];   // slot 1 is free post-loop
  if (tid < 256) {
    int grow = row0 + bm * 256 + tid;
    batchLS[tid] = (grow < Nn) ? batch[grow] : -1;
  }
  float bv[4];
#pragma unroll
  for (int nn = 0; nn < 4; ++nn) bv[nn] = bias[bn * 256 + wn * 64 + nn * 16 + lc];

#pragma unroll
  for (int r = 0; r < 2; ++r) {
    if ((wm >> 1) == r) {
#pragma unroll
      for (int mm = 0; mm < 4; ++mm) {
#pragma unroll
        for (int nn = 0; nn < 4; ++nn) {
          int lcol = wn * 64 + nn * 16 + lc;
#pragma unroll
          for (int j = 0; j < 4; ++j) {
            int lrow = (wm & 1) * 64 + mm * 16 + (l >> 4) * 4 + j;
            float v = fmaxf(acc[mm][nn][j] + bv[nn], 0.0f);
            eps[lrow * 256 + (lcol ^ (((lrow >> 2) & 3) << 4))] = f2bf(v);
          }
        }
      }
    }
    BARM();
    // column scan: thread -> (col = tid&255, rows qt*32..qt*32+31)
    {
      int col = tid & 255;
      int qt = tid >> 8;                   // 0..3
      int gcur = -2;
      float run = 0.f;
      int gcolbase = bn * 256 + col;
      for (int i = 0; i < 32; ++i) {
        int lr = qt * 32 + i;
        int g = batchLS[r * 128 + lr];
        if (g != gcur) {
          if (gcur >= 0) atomicAdd(&part[(size_t)gcur * N + gcolbase], run);
          gcur = g; run = 0.f;
        }
        run += bf2f(eps[lr * 256 + (col ^ (((lr >> 2) & 3) << 4))]);
      }
      if (gcur >= 0) atomicAdd(&part[(size_t)gcur * N + gcolbase], run);
    }
    BARM();
  }
}

// ---------------- pool finalize ----------------
__global__ void zero_part(float* __restrict__ part, int n) {
  int i = blockIdx.x * blockDim.x + threadIdx.x;
  if (i < n) part[i] = 0.f;
}

__global__ void pool_div(const float* __restrict__ part, const int* __restrict__ batch,
                         float* __restrict__ out, int n, int D, int G) {
  int idx = blockIdx.x * blockDim.x + threadIdx.x;
  if (idx >= G * D) return;
  int g = idx / D;
  int lo, hi;
  { int a = 0, b = n; while (a < b) { int m = (a + b) >> 1; if (batch[m] < g) a = m + 1; else b = m; } lo = a; }
  { int a = lo, b = n; while (a < b) { int m = (a + b) >> 1; if (batch[m] < g + 1) a = m + 1; else b = m; } hi = a; }
  out[idx] = part[idx] / (float)(hi - lo);
}

// ---------------- launcher ----------------
static inline size_t align256(size_t x) { return (x + 255) & ~(size_t)255; }

extern "C" void kernel_launch(void* const* d_in, const int* in_sizes, int n_in,
                              void* d_out, int out_size, void* d_ws, size_t ws_size,
                              hipStream_t stream) {
  const float* x = (const float*)d_in[0];
  // d_in[1] = edge_index (unused by the math)
  const int* batch = (const int*)d_in[2];
  const float* W0 = (const float*)d_in[3];
  const float* b0 = (const float*)d_in[4];
  const float* W1 = (const float*)d_in[5];
  const float* b1 = (const float*)d_in[6];
  const float* W2 = (const float*)d_in[7];
  const float* b2 = (const float*)d_in[8];
  float* out = (float*)d_out;

  const int Nn = in_sizes[2];                 // 100000 nodes
  const int DIN = 512, DH = 1024, DOUT = 512;
  const int G = out_size / DOUT;              // 128
  const int Mpad = ((Nn + 255) / 256) * 256;  // 100096

  // workspace layout (h2 eliminated)
  uint8_t* p = (uint8_t*)d_ws;
  unsigned short* W0t = (unsigned short*)p; p += align256((size_t)DH * DIN * 2);
  unsigned short* W1t = (unsigned short*)p; p += align256((size_t)DH * DH * 2);
  unsigned short* W2t = (unsigned short*)p; p += align256((size_t)DOUT * DH * 2);
  float* part         = (float*)p;          p += align256((size_t)G * DOUT * 4);
  size_t used = (size_t)(p - (uint8_t*)d_ws);
  size_t avail = ws_size > used ? ws_size - used : 0;
  size_t per_row = (size_t)(DIN + DH + DH) * 2;       // xb + h0 + h1 bytes per row
  long long chl = (long long)(avail / per_row);
  chl = (chl / 256) * 256;
  int CH = (int)(chl < 256 ? 256 : chl);
  if (CH > Mpad) CH = Mpad;
  unsigned short* xb = (unsigned short*)p; p += align256((size_t)CH * DIN * 2);
  unsigned short* h0 = (unsigned short*)p; p += align256((size_t)CH * DH * 2);
  unsigned short* h1 = (unsigned short*)p; p += align256((size_t)CH * DH * 2);

  // 0) zero the pooling accumulators
  zero_part<<<dim3((G * DOUT + 255) / 256), 256, 0, stream>>>(part, G * DOUT);

  // 1) weights: transpose + convert to bf16 [N][K]
  transpose_w<<<dim3((DIN / 32) * (DH / 32)), 256, 0, stream>>>(W0, W0t, DIN, DH);
  transpose_w<<<dim3((DH / 32) * (DH / 32)), 256, 0, stream>>>(W1, W1t, DH, DH);
  transpose_w<<<dim3((DH / 32) * (DOUT / 32)), 256, 0, stream>>>(W2, W2t, DH, DOUT);

  // 2) chunked 3-layer MLP (single chunk when ws allows); L2 fuses the pool
  for (int off = 0; off < Mpad; off += CH) {
    int rows = Mpad - off; if (rows > CH) rows = CH;
    int nvalid = Nn - off;
    size_t cvt_threads = (size_t)rows * DIN / 8;
    int cvt_blocks = (int)((cvt_threads + 255) / 256);
    if (cvt_blocks > 2048) cvt_blocks = 2048;
    cvt_x<<<dim3(cvt_blocks), 256, 0, stream>>>(x + (size_t)off * DIN, xb, rows, nvalid, DIN);

    gemm256<<<dim3((rows / 256) * (DH / 256)), 1024, 0, stream>>>(xb, W0t, b0, h0, DH, DIN);
    gemm256<<<dim3((rows / 256) * (DH / 256)), 1024, 0, stream>>>(h0, W1t, b1, h1, DH, DH);
    gemm_pool<<<dim3((rows / 256) * (DOUT / 256)), 1024, 0, stream>>>(
        h1, W2t, b2, batch, part, DOUT, DH, off, Nn);
  }

  // 3) finalize: mean = sum / count
  pool_div<<<dim3((G * DOUT + 255) / 256), 256, 0, stream>>>(part, batch, out, Nn, DOUT, G);
}

// Round 12
// 648.347 us; speedup vs baseline: 1.0698x; 1.0169x over previous
//
#include <hip/hip_runtime.h>
#include <cstdint>
#include <cstddef>

// ---------------- types / helpers ----------------
typedef __bf16 bf16x8 __attribute__((ext_vector_type(8)));
typedef float f32x4 __attribute__((ext_vector_type(4)));

__device__ __forceinline__ unsigned short f2bf(float f) {
  unsigned u = __float_as_uint(f);
  u += 0x7fffu + ((u >> 16) & 1u);   // RNE
  return (unsigned short)(u >> 16);
}
__device__ __forceinline__ float bf2f(unsigned short s) {
  return __uint_as_float(((unsigned)s) << 16);
}

// async global->LDS, 16B per lane, linear dest (wave-uniform base + lane*16)
__device__ __forceinline__ void gld_lds16(const void* g, void* l) {
  __builtin_amdgcn_global_load_lds(
      (const __attribute__((address_space(1))) void*)g,
      (__attribute__((address_space(3))) void*)l, 16, 0, 0);
}

#define BARM() do { __builtin_amdgcn_s_barrier(); asm volatile("" ::: "memory"); } while (0)
#define VMCNT(n) asm volatile("s_waitcnt vmcnt(" #n ")" ::: "memory")
// lgkmcnt(0) WITHOUT sched_barrier: certifies this wave's ds_reads complete
// before the following BARM (asm-asm ordering); MFMAs remain free to schedule
// anywhere between the reads and here (rule #18 cuts the other way: reg-only
// MFMA floating past this wait is exactly the read/MFMA overlap we want).
#define LGKMW() asm volatile("s_waitcnt lgkmcnt(0)" ::: "memory")

// ---------------- transpose + convert W [K][N] f32 -> Wt [N][K] bf16 ----------------
__global__ void transpose_w(const float* __restrict__ w, unsigned short* __restrict__ wt,
                            int K, int N) {
  __shared__ float tile[32][33];
  int nt = N >> 5;
  int bx = blockIdx.x % nt;   // n tile
  int by = blockIdx.x / nt;   // k tile
  int tx = threadIdx.x & 31, ty = threadIdx.x >> 5;  // 32x8
#pragma unroll
  for (int r = 0; r < 32; r += 8)
    tile[ty + r][tx] = w[(size_t)(by * 32 + ty + r) * N + bx * 32 + tx];
  __syncthreads();
#pragma unroll
  for (int r = 0; r < 32; r += 8)
    wt[(size_t)(bx * 32 + ty + r) * K + by * 32 + tx] = f2bf(tile[tx][ty + r]);
}

// ---------------- x f32 -> bf16 (chunk, zero-pad rows >= nvalid) ----------------
__global__ void cvt_x(const float* __restrict__ x, unsigned short* __restrict__ xb,
                      int rows, int nvalid, int D) {
  size_t total = (size_t)rows * D / 8;
  for (size_t i = (size_t)blockIdx.x * blockDim.x + threadIdx.x; i < total;
       i += (size_t)gridDim.x * blockDim.x) {
    size_t e = i * 8;
    int row = (int)(e / (size_t)D);
    uint4 ov;
    if (row < nvalid) {
      const float4* s = (const float4*)(x + e);
      float4 v0 = s[0], v1 = s[1];
      ov.x = (unsigned)f2bf(v0.x) | ((unsigned)f2bf(v0.y) << 16);
      ov.y = (unsigned)f2bf(v0.z) | ((unsigned)f2bf(v0.w) << 16);
      ov.z = (unsigned)f2bf(v1.x) | ((unsigned)f2bf(v1.y) << 16);
      ov.w = (unsigned)f2bf(v1.z) | ((unsigned)f2bf(v1.w) << 16);
    } else {
      ov.x = ov.y = ov.z = ov.w = 0u;
    }
    *(uint4*)(xb + e) = ov;
  }
}

// ---------------- 256x256 GEMM, 16 waves, 2-barrier/K64 relaxed schedule ----------------
// Round-12 change vs r11: drop the per-phase lockstep (8 barriers + 4 pinned
// lgkm0+sched_barrier per K64) for 2 barriers + 1 counted vmcnt per K64, and
// let the compiler interleave ds_reads with MFMAs (fine-grained lgkmcnt).
// Race proof:
//  (1) staged-data-ready: per-wave VMCNT(2) at tile t retires the 4 oldest
//      gld_lds = tile t+1 k0 (issued t-1, 2nd half) + k1 (issued t, 1st half);
//      the following BAR makes certification collective before t+1's reads.
//  (2) no overwrite of live reads: writes into slot-s k0 (stage at t's 2nd
//      half) issue only after the mid-tile BAR, which every wave reaches only
//      after its LGKMW certified its k0 ds_reads complete. Same for k1 via the
//      end-of-tile BAR gating t+1's 1st-half stage into slot-s k1.
//  (3) gld_lds/ds_read are memory ops: cannot cross BARM's memory clobber.
__device__ __forceinline__ bf16x8 read_frag(const unsigned short* region, int row, int kel) {
  int ke = kel ^ (((row >> 1) & 3) << 3);
  return *(const bf16x8*)(region + row * 32 + ke);
}

__device__ __forceinline__ void stage_half(const unsigned short* gpanel, int K, int kofs,
                                           unsigned short* region, int tid) {
  int row = tid >> 2;                                  // 1024 threads -> 256 rows x 4
  int ke = ((tid & 3) * 8) ^ (((row >> 1) & 3) << 3);  // inverse-swizzled source
  gld_lds16(gpanel + (size_t)row * K + kofs + ke, region + tid * 8);
}

#define MFMA16X(BV)                                                             \
  _Pragma("unroll") for (int mm = 0; mm < 4; ++mm)                              \
      _Pragma("unroll") for (int nn = 0; nn < 4; ++nn)                          \
          acc[mm][nn] = __builtin_amdgcn_mfma_f32_16x16x32_bf16(                \
              av[mm], BV[nn], acc[mm][nn], 0, 0, 0)

// Shared K-loop body. Defines acc[4][4]; caller provides epilogue.
#define GEMM_PREAMBLE_AND_KLOOP()                                               \
  const int tid = threadIdx.x;                                                  \
  const int w = tid >> 6, l = tid & 63;                                         \
  const int wm = w >> 2, wn = w & 3;                                            \
  const int lc = l & 15, lk8 = (l >> 4) * 8;                                    \
  const int nbn = N >> 8;                                                       \
  const int nwg = gridDim.x;                                                    \
  const int q = nwg >> 3, rr = nwg & 7;                                         \
  const int xcd = blockIdx.x & 7, ib = blockIdx.x >> 3;                         \
  const int bswz = (xcd < rr ? xcd * (q + 1) : rr * (q + 1) + (xcd - rr) * q) + ib; \
  const int bm = bswz / nbn, bn = bswz - bm * nbn;                              \
  const unsigned short* Ap = A + (size_t)bm * 256 * K;                          \
  const unsigned short* Bp = Bt + (size_t)bn * 256 * K;                         \
  const int T = K >> 6;                                                         \
  f32x4 acc[4][4] = {};                                                         \
  stage_half(Ap, K, 0, &lds[0][0][0][0][0], tid);                               \
  stage_half(Bp, K, 0, &lds[0][1][0][0][0], tid);                               \
  stage_half(Ap, K, 32, &lds[0][0][1][0][0], tid);                              \
  stage_half(Bp, K, 32, &lds[0][1][1][0][0], tid);                              \
  stage_half(Ap, K, 64, &lds[1][0][0][0][0], tid);                              \
  stage_half(Bp, K, 64, &lds[1][1][0][0][0], tid);                              \
  VMCNT(2);                                                                     \
  BARM();                                                                       \
  for (int t = 0; t < T; ++t) {                                                 \
    const int s = t & 1;                                                        \
    const unsigned short* Ak0 = &lds[s][0][0][0][0];                            \
    const unsigned short* Ak1 = &lds[s][0][1][0][0];                            \
    const unsigned short* Bk0 = &lds[s][1][0][0][0];                            \
    const unsigned short* Bk1 = &lds[s][1][1][0][0];                            \
    unsigned short* nAk1 = &lds[s ^ 1][0][1][0][0];                             \
    unsigned short* nBk1 = &lds[s ^ 1][1][1][0][0];                             \
    unsigned short* cAk0 = &lds[s][0][0][0][0];                                 \
    unsigned short* cBk0 = &lds[s][1][0][0][0];                                 \
    bf16x8 av[4], bq[4];                                                        \
    /* ---- half 0 (k0) ---- */                                                 \
    _Pragma("unroll") for (int mm = 0; mm < 4; ++mm)                            \
        av[mm] = read_frag(Ak0, wm * 64 + mm * 16 + lc, lk8);                   \
    _Pragma("unroll") for (int nn = 0; nn < 4; ++nn)                            \
        bq[nn] = read_frag(Bk0, wn * 64 + nn * 16 + lc, lk8);                   \
    if (t + 1 < T) {                                                            \
      stage_half(Ap, K, (t + 1) * 64 + 32, nAk1, tid);                          \
      stage_half(Bp, K, (t + 1) * 64 + 32, nBk1, tid);                          \
    }                                                                           \
    MFMA16X(bq);                                                                \
    LGKMW();                                                                    \
    BARM();   /* k0-region reads certified; gates the stage below */            \
    /* ---- half 1 (k1) ---- */                                                 \
    _Pragma("unroll") for (int mm = 0; mm < 4; ++mm)                            \
        av[mm] = read_frag(Ak1, wm * 64 + mm * 16 + lc, lk8);                   \
    _Pragma("unroll") for (int nn = 0; nn < 4; ++nn)                            \
        bq[nn] = read_frag(Bk1, wn * 64 + nn * 16 + lc, lk8);                   \
    if (t + 2 < T) {                                                            \
      stage_half(Ap, K, (t + 2) * 64, cAk0, tid);                               \
      stage_half(Bp, K, (t + 2) * 64, cBk0, tid);                               \
    }                                                                           \
    MFMA16X(bq);                                                                \
    LGKMW();                                                                    \
    if (t + 2 < T) { VMCNT(2); } else { VMCNT(0); }                             \
    BARM();   /* tile t+1 certified collectively; k1 reads certified */         \
  }

__global__ __launch_bounds__(1024, 1) void gemm256(
    const unsigned short* __restrict__ A,   // [M][K] bf16
    const unsigned short* __restrict__ Bt,  // [N][K] bf16
    const float* __restrict__ bias,         // [N] f32
    unsigned short* __restrict__ C,         // [M][N] bf16
    int N, int K) {
  __shared__ alignas(16) unsigned short lds[2][2][2][256][32];   // 128 KiB
  GEMM_PREAMBLE_AND_KLOOP();

  // ---- epilogue: acc -> LDS (row-XOR swizzle) -> coalesced dwordx4 stores ----
  unsigned short* eps = &lds[0][0][0][0][0];   // [128][256] bf16 per round
  float bv[4];
#pragma unroll
  for (int nn = 0; nn < 4; ++nn) bv[nn] = bias[bn * 256 + wn * 64 + nn * 16 + lc];

#pragma unroll
  for (int r = 0; r < 2; ++r) {
    if ((wm >> 1) == r) {                      // waves wm=2r,2r+1 own rows r*128..+127
#pragma unroll
      for (int mm = 0; mm < 4; ++mm) {
#pragma unroll
        for (int nn = 0; nn < 4; ++nn) {
          int lcol = wn * 64 + nn * 16 + lc;
#pragma unroll
          for (int j = 0; j < 4; ++j) {
            int lrow = (wm & 1) * 64 + mm * 16 + (l >> 4) * 4 + j;
            float v = fmaxf(acc[mm][nn][j] + bv[nn], 0.0f);
            eps[lrow * 256 + (lcol ^ (((lrow >> 2) & 3) << 4))] = f2bf(v);
          }
        }
      }
    }
    BARM();
#pragma unroll
    for (int it = 0; it < 4; ++it) {
      int flat = it * 1024 + tid;          // 4096 = 128 rows x 32 col-granules
      int lrow = flat >> 5, cb = flat & 31;
      int ce = (cb * 8) ^ (((lrow >> 2) & 3) << 4);
      uint4 v = *(const uint4*)&eps[lrow * 256 + ce];
      *(uint4*)&C[(size_t)(bm * 256 + r * 128 + lrow) * N + bn * 256 + cb * 8] = v;
    }
    BARM();
  }
}

// Last layer: identical K-loop; segment-sum relu'd outputs per graph via
// atomicAdd into part[G][N] (batch sorted; pad rows -> sentinel -1).
__global__ __launch_bounds__(1024, 1) void gemm_pool(
    const unsigned short* __restrict__ A,   // [M][K] bf16 (chunk base)
    const unsigned short* __restrict__ Bt,  // [N][K] bf16
    const float* __restrict__ bias,         // [N] f32
    const int* __restrict__ batch,          // [Nn] sorted graph ids (global)
    float* __restrict__ part,               // [G][N] f32 accumulators
    int N, int K, int row0, int Nn) {       // row0 = chunk offset in global rows
  __shared__ alignas(16) unsigned short lds[2][2][2][256][32];   // 128 KiB
  GEMM_PREAMBLE_AND_KLOOP();

  unsigned short* eps = &lds[0][0][0][0][0];
  int* batchLS = (int*)&lds[1][0][0][0][0];   // slot 1 is free post-loop
  if (tid < 256) {
    int grow = row0 + bm * 256 + tid;
    batchLS[tid] = (grow < Nn) ? batch[grow] : -1;
  }
  float bv[4];
#pragma unroll
  for (int nn = 0; nn < 4; ++nn) bv[nn] = bias[bn * 256 + wn * 64 + nn * 16 + lc];

#pragma unroll
  for (int r = 0; r < 2; ++r) {
    if ((wm >> 1) == r) {
#pragma unroll
      for (int mm = 0; mm < 4; ++mm) {
#pragma unroll
        for (int nn = 0; nn < 4; ++nn) {
          int lcol = wn * 64 + nn * 16 + lc;
#pragma unroll
          for (int j = 0; j < 4; ++j) {
            int lrow = (wm & 1) * 64 + mm * 16 + (l >> 4) * 4 + j;
            float v = fmaxf(acc[mm][nn][j] + bv[nn], 0.0f);
            eps[lrow * 256 + (lcol ^ (((lrow >> 2) & 3) << 4))] = f2bf(v);
          }
        }
      }
    }
    BARM();
    // column scan: thread -> (col = tid&255, rows qt*32..qt*32+31)
    {
      int col = tid & 255;
      int qt = tid >> 8;                   // 0..3
      int gcur = -2;
      float run = 0.f;
      int gcolbase = bn * 256 + col;
      for (int i = 0; i < 32; ++i) {
        int lr = qt * 32 + i;
        int g = batchLS[r * 128 + lr];
        if (g != gcur) {
          if (gcur >= 0) atomicAdd(&part[(size_t)gcur * N + gcolbase], run);
          gcur = g; run = 0.f;
        }
        run += bf2f(eps[lr * 256 + (col ^ (((lr >> 2) & 3) << 4))]);
      }
      if (gcur >= 0) atomicAdd(&part[(size_t)gcur * N + gcolbase], run);
    }
    BARM();
  }
}

// ---------------- pool finalize ----------------
__global__ void zero_part(float* __restrict__ part, int n) {
  int i = blockIdx.x * blockDim.x + threadIdx.x;
  if (i < n) part[i] = 0.f;
}

__global__ void pool_div(const float* __restrict__ part, const int* __restrict__ batch,
                         float* __restrict__ out, int n, int D, int G) {
  int idx = blockIdx.x * blockDim.x + threadIdx.x;
  if (idx >= G * D) return;
  int g = idx / D;
  int lo, hi;
  { int a = 0, b = n; while (a < b) { int m = (a + b) >> 1; if (batch[m] < g) a = m + 1; else b = m; } lo = a; }
  { int a = lo, b = n; while (a < b) { int m = (a + b) >> 1; if (batch[m] < g + 1) a = m + 1; else b = m; } hi = a; }
  out[idx] = part[idx] / (float)(hi - lo);
}

// ---------------- launcher ----------------
static inline size_t align256(size_t x) { return (x + 255) & ~(size_t)255; }

extern "C" void kernel_launch(void* const* d_in, const int* in_sizes, int n_in,
                              void* d_out, int out_size, void* d_ws, size_t ws_size,
                              hipStream_t stream) {
  const float* x = (const float*)d_in[0];
  // d_in[1] = edge_index (unused by the math)
  const int* batch = (const int*)d_in[2];
  const float* W0 = (const float*)d_in[3];
  const float* b0 = (const float*)d_in[4];
  const float* W1 = (const float*)d_in[5];
  const float* b1 = (const float*)d_in[6];
  const float* W2 = (const float*)d_in[7];
  const float* b2 = (const float*)d_in[8];
  float* out = (float*)d_out;

  const int Nn = in_sizes[2];                 // 100000 nodes
  const int DIN = 512, DH = 1024, DOUT = 512;
  const int G = out_size / DOUT;              // 128
  const int Mpad = ((Nn + 255) / 256) * 256;  // 100096

  // workspace layout (h2 eliminated)
  uint8_t* p = (uint8_t*)d_ws;
  unsigned short* W0t = (unsigned short*)p; p += align256((size_t)DH * DIN * 2);
  unsigned short* W1t = (unsigned short*)p; p += align256((size_t)DH * DH * 2);
  unsigned short* W2t = (unsigned short*)p; p += align256((size_t)DOUT * DH * 2);
  float* part         = (float*)p;          p += align256((size_t)G * DOUT * 4);
  size_t used = (size_t)(p - (uint8_t*)d_ws);
  size_t avail = ws_size > used ? ws_size - used : 0;
  size_t per_row = (size_t)(DIN + DH + DH) * 2;       // xb + h0 + h1 bytes per row
  long long chl = (long long)(avail / per_row);
  chl = (chl / 256) * 256;
  int CH = (int)(chl < 256 ? 256 : chl);
  if (CH > Mpad) CH = Mpad;
  unsigned short* xb = (unsigned short*)p; p += align256((size_t)CH * DIN * 2);
  unsigned short* h0 = (unsigned short*)p; p += align256((size_t)CH * DH * 2);
  unsigned short* h1 = (unsigned short*)p; p += align256((size_t)CH * DH * 2);

  // 0) zero the pooling accumulators
  zero_part<<<dim3((G * DOUT + 255) / 256), 256, 0, stream>>>(part, G * DOUT);

  // 1) weights: transpose + convert to bf16 [N][K]
  transpose_w<<<dim3((DIN / 32) * (DH / 32)), 256, 0, stream>>>(W0, W0t, DIN, DH);
  transpose_w<<<dim3((DH / 32) * (DH / 32)), 256, 0, stream>>>(W1, W1t, DH, DH);
  transpose_w<<<dim3((DH / 32) * (DOUT / 32)), 256, 0, stream>>>(W2, W2t, DH, DOUT);

  // 2) chunked 3-layer MLP (single chunk when ws allows); L2 fuses the pool
  for (int off = 0; off < Mpad; off += CH) {
    int rows = Mpad - off; if (rows > CH) rows = CH;
    int nvalid = Nn - off;
    size_t cvt_threads = (size_t)rows * DIN / 8;
    int cvt_blocks = (int)((cvt_threads + 255) / 256);
    if (cvt_blocks > 2048) cvt_blocks = 2048;
    cvt_x<<<dim3(cvt_blocks), 256, 0, stream>>>(x + (size_t)off * DIN, xb, rows, nvalid, DIN);

    gemm256<<<dim3((rows / 256) * (DH / 256)), 1024, 0, stream>>>(xb, W0t, b0, h0, DH, DIN);
    gemm256<<<dim3((rows / 256) * (DH / 256)), 1024, 0, stream>>>(h0, W1t, b1, h1, DH, DH);
    gemm_pool<<<dim3((rows / 256) * (DOUT / 256)), 1024, 0, stream>>>(
        h1, W2t, b2, batch, part, DOUT, DH, off, Nn);
  }

  // 3) finalize: mean = sum / count
  pool_div<<<dim3((G * DOUT + 255) / 256), 256, 0, stream>>>(part, batch, out, Nn, DOUT, G);
}